// Round 2
// baseline (460.741 us; speedup 1.0000x reference)
//
#include <hip/hip_runtime.h>

typedef __attribute__((ext_vector_type(8))) unsigned short ushort8_t;
typedef __attribute__((ext_vector_type(8))) __bf16 bf16x8;
typedef __attribute__((ext_vector_type(16))) float f32x16;

#define NSEG 2176   // 32 styles * 68 comps
#define NITEM 1536  // B*3

__device__ inline unsigned short f2bf(float f) {
    unsigned int b = __builtin_bit_cast(unsigned int, f);
    b += 0x7FFFu + ((b >> 16) & 1u);   // round-to-nearest-even
    return (unsigned short)(b >> 16);
}
__device__ inline float bf2f(unsigned short h) {
    unsigned int b = ((unsigned int)h) << 16;
    return __builtin_bit_cast(float, b);
}

// ---------------- Kernel A: keys + CSR (single block) ----------------
__global__ __launch_bounds__(256) void kA(const int* __restrict__ style,
                                          const int* __restrict__ cids,
                                          int* __restrict__ addr_g, int* __restrict__ key_g,
                                          int* __restrict__ rank_g, int* __restrict__ list_g,
                                          int* __restrict__ segstart_g, int* __restrict__ segcnt_g) {
    __shared__ int cnt[NSEG];
    __shared__ int sstart[NSEG];
    __shared__ int partial[256];
    const int tid = threadIdx.x;
    for (int s = tid; s < NSEG; s += 256) cnt[s] = 0;
    __syncthreads();
    int myrank[6], mykey[6];
    #pragma unroll
    for (int k = 0; k < 6; ++k) {
        const int i = k * 256 + tid;
        const int b = i / 3, j = i - b * 3;
        const int off = (j == 0) ? 0 : (j == 1) ? 19 : 40;
        const int a = cids[i] + off;
        const int key = style[b] * 68 + a;
        addr_g[i] = a; key_g[i] = key;
        mykey[k] = key;
        myrank[k] = atomicAdd(&cnt[key], 1);
        rank_g[i] = myrank[k];
    }
    __syncthreads();
    const int base = tid * 9;
    int ssum = 0;
    for (int q = 0; q < 9; ++q) { int s = base + q; if (s < NSEG) ssum += cnt[s]; }
    partial[tid] = ssum;
    __syncthreads();
    if (tid == 0) {
        int run = 0;
        for (int t = 0; t < 256; ++t) { int tmp = partial[t]; partial[t] = run; run += tmp; }
    }
    __syncthreads();
    int run = partial[tid];
    for (int q = 0; q < 9; ++q) {
        int s = base + q;
        if (s < NSEG) { sstart[s] = run; segstart_g[s] = run; segcnt_g[s] = cnt[s]; run += cnt[s]; }
    }
    __syncthreads();
    #pragma unroll
    for (int k = 0; k < 6; ++k) {
        const int i = k * 256 + tid;
        list_g[sstart[mykey[k]] + myrank[k]] = i;
    }
}

// ------------- Kernel W: weight repack -> Bp[kb][co][8] bf16, k=(tap,ci) -------------
__global__ __launch_bounds__(256) void kW(const float* __restrict__ w1,
                                          const float* __restrict__ w2,
                                          const float* __restrict__ w3,
                                          unsigned short* __restrict__ Bp) {
    const int t = blockIdx.x * 256 + threadIdx.x;
    if (t >= 3 * 147456) return;
    const int l = t / 147456;
    const int o = t - l * 147456;
    const int slot = o & 7;
    const int co = (o >> 3) & 127;
    const int kb = o >> 10;
    const int tap = kb >> 4;
    const int ci = ((kb & 15) << 3) | slot;
    const float* w = (l == 0) ? w1 : (l == 1) ? w2 : w3;
    Bp[t] = f2bf(w[(co * 128 + ci) * 9 + tap]);
}

// ------------- Kernel C: one conv+relu layer, one block per comp image -------------
// LDS holds input image as [m=h*16+w][ci] bf16, byte ^= (m&15)<<4 swizzle.
// Implicit GEMM: out[m,co] = sum_{tap,ci} in[m2(tap)][ci] * w[co,ci,tap]
// mfma_f32_32x32x16_bf16: A row=l&31 k=(l>>5)*8+j ; B col=l&31 same k ; D col=l&31 row=(r&3)+8*(r>>2)+4*(l>>5)
__global__ __launch_bounds__(256) void kConv(const float* __restrict__ bias_in,
                                             const unsigned short* __restrict__ inter_in,
                                             const unsigned short* __restrict__ Bp,
                                             const float* __restrict__ bvec,
                                             unsigned short* __restrict__ inter_out,
                                             unsigned short* __restrict__ pbu_out,
                                             int layer) {
    extern __shared__ char lds[];
    const int tid = threadIdx.x;
    const int u = blockIdx.x;

    if (layer == 0) {
        // bias is [C][H][W]; transpose to [m][ci] with swizzle
        const float* src = bias_in + (size_t)u * 32768;
        const int m = tid;
        const int swz = (m & 15) << 4;
        #pragma unroll 4
        for (int c = 0; c < 128; ++c) {
            const float v = src[c * 256 + m];
            const int off = (m * 256 + c * 2) ^ swz;
            *(unsigned short*)(lds + off) = f2bf(v);
        }
    } else {
        // inter already stored swizzled: linear 64KB copy
        const uint4* src = (const uint4*)(inter_in + (size_t)u * 32768);
        uint4* dst = (uint4*)lds;
        #pragma unroll
        for (int r = 0; r < 16; ++r) dst[r * 256 + tid] = src[r * 256 + tid];
    }
    __syncthreads();

    const int lane = tid & 63;
    const int wid = tid >> 6;
    const int wm = wid >> 1;   // M tiles [wm*4, wm*4+4)
    const int wn = wid & 1;    // N tiles [wn*2, wn*2+2)
    const int lrow = lane & 31;
    const int lhi = lane >> 5;

    f32x16 acc[4][2] = {};

    for (int kk = 0; kk < 72; ++kk) {
        const int tap = kk >> 3;
        const int oh = tap / 3 - 1;
        const int ow = tap % 3 - 1;
        const int ci0 = (kk & 7) * 16 + lhi * 8;
        const int kb = kk * 2 + lhi;

        bf16x8 bfrag[2];
        #pragma unroll
        for (int t2 = 0; t2 < 2; ++t2) {
            const int co = (wn * 2 + t2) * 32 + lrow;
            bfrag[t2] = __builtin_bit_cast(bf16x8,
                *(const ushort8_t*)(Bp + ((size_t)(kb * 128 + co)) * 8));
        }
        bf16x8 afrag[4];
        #pragma unroll
        for (int t = 0; t < 4; ++t) {
            const int m = (wm * 4 + t) * 32 + lrow;
            const int h = (m >> 4) + oh;
            const int w = (m & 15) + ow;
            ushort8_t v = {0, 0, 0, 0, 0, 0, 0, 0};
            if ((unsigned)h < 16u && (unsigned)w < 16u) {
                const int m2 = h * 16 + w;
                const int off = (m2 * 256 + ci0 * 2) ^ ((m2 & 15) << 4);
                v = *(const ushort8_t*)(lds + off);
            }
            afrag[t] = __builtin_bit_cast(bf16x8, v);
        }
        #pragma unroll
        for (int t = 0; t < 4; ++t)
            #pragma unroll
            for (int t2 = 0; t2 < 2; ++t2)
                acc[t][t2] = __builtin_amdgcn_mfma_f32_32x32x16_bf16(
                    afrag[t], bfrag[t2], acc[t][t2], 0, 0, 0);
    }

    // epilogue: +bias, relu, store
    #pragma unroll
    for (int t2 = 0; t2 < 2; ++t2) {
        const int co = (wn * 2 + t2) * 32 + lrow;
        const float bb = bvec[co];
        #pragma unroll
        for (int t = 0; t < 4; ++t) {
            const int tmb = (wm * 4 + t) * 32;
            if (layer < 2) {
                #pragma unroll
                for (int r = 0; r < 16; ++r) {
                    const int m = tmb + (r & 3) + 8 * (r >> 2) + 4 * lhi;
                    const float v = fmaxf(acc[t][t2][r] + bb, 0.0f);
                    const int off = (m * 256 + co * 2) ^ ((m & 15) << 4);
                    *(unsigned short*)((char*)inter_out + (size_t)u * 65536 + off) = f2bf(v);
                }
            } else {
                // pbu in [u][co][m] (CHW) layout, bf16, packed 4-wide along m
                #pragma unroll
                for (int rq = 0; rq < 4; ++rq) {
                    const int m0 = tmb + 8 * rq + 4 * lhi;
                    ushort4 pk;
                    pk.x = f2bf(fmaxf(acc[t][t2][rq * 4 + 0] + bb, 0.0f));
                    pk.y = f2bf(fmaxf(acc[t][t2][rq * 4 + 1] + bb, 0.0f));
                    pk.z = f2bf(fmaxf(acc[t][t2][rq * 4 + 2] + bb, 0.0f));
                    pk.w = f2bf(fmaxf(acc[t][t2][rq * 4 + 3] + bb, 0.0f));
                    *(ushort4*)(pbu_out + (size_t)u * 32768 + co * 256 + m0) = pk;
                }
            }
        }
    }
}

// ------------- Kernel B: segment mean (leader) + broadcast + pbu add -------------
__global__ __launch_bounds__(256) void kB(const float* __restrict__ feats,
                                          const unsigned short* __restrict__ pbu,
                                          const int* __restrict__ addr_g,
                                          const int* __restrict__ key_g,
                                          const int* __restrict__ rank_g,
                                          const int* __restrict__ list_g,
                                          const int* __restrict__ segstart_g,
                                          const int* __restrict__ segcnt_g,
                                          float* __restrict__ out) {
    const int i = blockIdx.y;
    if (rank_g[i] != 0) return;          // only segment leaders work
    const int s = key_g[i];
    const int st = segstart_g[s];
    const int n = segcnt_g[s];
    const int e = blockIdx.x * 1024 + threadIdx.x * 4;
    float sx = 0.f, sy = 0.f, sz = 0.f, sw = 0.f;
    for (int t = 0; t < n; ++t) {
        const int j = list_g[st + t];
        const float4 v = *(const float4*)(feats + (size_t)j * 32768 + e);
        sx += v.x; sy += v.y; sz += v.z; sw += v.w;
    }
    const float inv = 1.0f / (float)n;
    sx *= inv; sy *= inv; sz *= inv; sw *= inv;
    for (int t = 0; t < n; ++t) {
        const int j = list_g[st + t];
        const int a = addr_g[j];
        const ushort4 p = *(const ushort4*)(pbu + (size_t)a * 32768 + e);
        float4 o;
        o.x = sx + bf2f(p.x);
        o.y = sy + bf2f(p.y);
        o.z = sz + bf2f(p.z);
        o.w = sw + bf2f(p.w);
        *(float4*)(out + (size_t)j * 32768 + e) = o;
    }
}

extern "C" void kernel_launch(void* const* d_in, const int* in_sizes, int n_in,
                              void* d_out, int out_size, void* d_ws, size_t ws_size,
                              hipStream_t stream) {
    const int* style   = (const int*)d_in[0];
    const int* cids    = (const int*)d_in[1];
    const float* feats = (const float*)d_in[2];
    const float* bias  = (const float*)d_in[3];
    const float* w1    = (const float*)d_in[4];
    const float* b1    = (const float*)d_in[5];
    const float* w2    = (const float*)d_in[6];
    const float* b2    = (const float*)d_in[7];
    const float* w3    = (const float*)d_in[8];
    const float* b3    = (const float*)d_in[9];
    float* out = (float*)d_out;
    char* ws = (char*)d_ws;

    int* addr_g     = (int*)(ws + 0);
    int* key_g      = (int*)(ws + 6144);
    int* rank_g     = (int*)(ws + 12288);
    int* list_g     = (int*)(ws + 18432);
    int* segstart_g = (int*)(ws + 24576);
    int* segcnt_g   = (int*)(ws + 33280);
    unsigned short* Bp     = (unsigned short*)(ws + 65536);        // 3*147456 bf16 = 864KB
    unsigned short* interA = (unsigned short*)(ws + 1048576);      // 68*32768 bf16 = 4.25MB
    unsigned short* interB = (unsigned short*)(ws + 5505024);
    unsigned short* pbu    = (unsigned short*)(ws + 9961472);

    hipLaunchKernelGGL(kA, dim3(1), dim3(256), 0, stream,
                       style, cids, addr_g, key_g, rank_g, list_g, segstart_g, segcnt_g);
    hipLaunchKernelGGL(kW, dim3(1728), dim3(256), 0, stream, w1, w2, w3, Bp);
    hipLaunchKernelGGL(kConv, dim3(68), dim3(256), 65536, stream,
                       bias, (const unsigned short*)nullptr, Bp, b1, interA,
                       (unsigned short*)nullptr, 0);
    hipLaunchKernelGGL(kConv, dim3(68), dim3(256), 65536, stream,
                       (const float*)nullptr, interA, Bp + 147456, b2, interB,
                       (unsigned short*)nullptr, 1);
    hipLaunchKernelGGL(kConv, dim3(68), dim3(256), 65536, stream,
                       (const float*)nullptr, interB, Bp + 2 * 147456, b3,
                       (unsigned short*)nullptr, pbu, 2);
    hipLaunchKernelGGL(kB, dim3(32, NITEM), dim3(256), 0, stream,
                       feats, pbu, addr_g, key_g, rank_g, list_g, segstart_g, segcnt_g, out);
}

// Round 3
// 431.052 us; speedup vs baseline: 1.0689x; 1.0689x over previous
//
#include <hip/hip_runtime.h>

typedef __attribute__((ext_vector_type(8))) unsigned short ushort8_t;
typedef __attribute__((ext_vector_type(8))) __bf16 bf16x8;
typedef __attribute__((ext_vector_type(16))) float f32x16;

#define NSEG 2176   // 32 styles * 68 comps
#define NITEM 1536  // B*3

__device__ inline unsigned short f2bf(float f) {
    unsigned int b = __builtin_bit_cast(unsigned int, f);
    b += 0x7FFFu + ((b >> 16) & 1u);   // round-to-nearest-even
    return (unsigned short)(b >> 16);
}
__device__ inline float bf2f(unsigned short h) {
    unsigned int b = ((unsigned int)h) << 16;
    return __builtin_bit_cast(float, b);
}

// ---------------- Kernel A: keys + CSR (single block) ----------------
__global__ __launch_bounds__(256) void kA(const int* __restrict__ style,
                                          const int* __restrict__ cids,
                                          int* __restrict__ addr_g, int* __restrict__ key_g,
                                          int* __restrict__ rank_g, int* __restrict__ list_g,
                                          int* __restrict__ segstart_g, int* __restrict__ segcnt_g) {
    __shared__ int cnt[NSEG];
    __shared__ int sstart[NSEG];
    __shared__ int partial[256];
    const int tid = threadIdx.x;
    const int lane = tid & 63;
    const int wid = tid >> 6;
    for (int s = tid; s < NSEG; s += 256) cnt[s] = 0;
    __syncthreads();
    int myrank[6], mykey[6];
    #pragma unroll
    for (int k = 0; k < 6; ++k) {
        const int i = k * 256 + tid;
        const int b = i / 3, j = i - b * 3;
        const int off = (j == 0) ? 0 : (j == 1) ? 19 : 40;
        const int a = cids[i] + off;
        const int key = style[b] * 68 + a;
        addr_g[i] = a; key_g[i] = key;
        mykey[k] = key;
        myrank[k] = atomicAdd(&cnt[key], 1);
        rank_g[i] = myrank[k];
    }
    __syncthreads();
    const int base = tid * 9;
    int ssum = 0;
    for (int q = 0; q < 9; ++q) { int s = base + q; if (s < NSEG) ssum += cnt[s]; }
    partial[tid] = ssum;
    __syncthreads();
    if (wid == 0) {
        // wave-parallel exclusive scan of partial[256]: 4 entries/lane
        int s0 = partial[lane * 4 + 0], s1 = partial[lane * 4 + 1];
        int s2 = partial[lane * 4 + 2], s3 = partial[lane * 4 + 3];
        const int loc = s0 + s1 + s2 + s3;
        int pre = loc;
        #pragma unroll
        for (int d = 1; d < 64; d <<= 1) {
            const int o = __shfl_up(pre, d);
            if (lane >= d) pre += o;
        }
        pre -= loc;  // exclusive
        partial[lane * 4 + 0] = pre;
        partial[lane * 4 + 1] = pre + s0;
        partial[lane * 4 + 2] = pre + s0 + s1;
        partial[lane * 4 + 3] = pre + s0 + s1 + s2;
    }
    __syncthreads();
    int run = partial[tid];
    for (int q = 0; q < 9; ++q) {
        int s = base + q;
        if (s < NSEG) { sstart[s] = run; segstart_g[s] = run; segcnt_g[s] = cnt[s]; run += cnt[s]; }
    }
    __syncthreads();
    #pragma unroll
    for (int k = 0; k < 6; ++k) {
        const int i = k * 256 + tid;
        list_g[sstart[mykey[k]] + myrank[k]] = i;
    }
}

// ------------- Kernel W: weight repack -> Bp[kb][co][8] bf16, k=(tap,ci) -------------
__global__ __launch_bounds__(256) void kW(const float* __restrict__ w1,
                                          const float* __restrict__ w2,
                                          const float* __restrict__ w3,
                                          unsigned short* __restrict__ Bp) {
    const int t = blockIdx.x * 256 + threadIdx.x;
    if (t >= 3 * 147456) return;
    const int l = t / 147456;
    const int o = t - l * 147456;
    const int slot = o & 7;
    const int co = (o >> 3) & 127;
    const int kb = o >> 10;
    const int tap = kb >> 4;
    const int ci = ((kb & 15) << 3) | slot;
    const float* w = (l == 0) ? w1 : (l == 1) ? w2 : w3;
    Bp[t] = f2bf(w[(co * 128 + ci) * 9 + tap]);
}

// ------------- Kernel CF: fused 3-layer conv+relu, one block per comp image -------------
// Single 64KB LDS buffer holds the activation as [m=h*16+w][ci] bf16, byte ^= (m&15)<<4.
// Implicit GEMM per layer: out[m,co] = sum_{tap,ci} act[m2(tap)][ci] * w[co,ci,tap]
// 512 threads = 8 waves (2/SIMD for TLP). Wave (wm=wid>>1, wn=wid&1) owns
// M-tiles {wm*2,wm*2+1} x N-tiles {wn*2,wn*2+1} of the 256x128 output.
// mfma_f32_32x32x16_bf16: A row=l&31, k=(l>>5)*8+j ; B col=l&31 same k ;
// D col=l&31, row=(r&3)+8*(r>>2)+4*(l>>5)
__global__ __launch_bounds__(512) void kConvF(const float* __restrict__ bias_in,
                                              const unsigned short* __restrict__ Bp,
                                              const float* __restrict__ b1,
                                              const float* __restrict__ b2,
                                              const float* __restrict__ b3,
                                              unsigned short* __restrict__ pbu_out) {
    __shared__ char lds[65536];
    const int tid = threadIdx.x;
    const int u = blockIdx.x;

    // Stage layer-0 input: bias[u] is [C][H*W]; transpose to [m][ci] bf16, swizzled.
    {
        const float* src = bias_in + (size_t)u * 32768;
        const int m = tid & 255;
        const int c0 = (tid >> 8) * 64;
        const int swz = (m & 15) << 4;
        #pragma unroll 4
        for (int c = c0; c < c0 + 64; ++c) {
            const float v = src[c * 256 + m];
            const int off = (m * 256 + c * 2) ^ swz;
            *(unsigned short*)(lds + off) = f2bf(v);
        }
    }
    __syncthreads();

    const int lane = tid & 63;
    const int wid = tid >> 6;
    const int wm = wid >> 1;   // 0..3 -> M tiles {wm*2, wm*2+1}
    const int wn = wid & 1;    // 0..1 -> N tiles {wn*2, wn*2+1}
    const int lrow = lane & 31;
    const int lhi = lane >> 5;

    for (int layer = 0; layer < 3; ++layer) {
        const unsigned short* Bpl = Bp + (size_t)layer * 147456;
        const float* bv = (layer == 0) ? b1 : (layer == 1) ? b2 : b3;

        f32x16 acc[2][2] = {};

        #pragma unroll 2
        for (int kk = 0; kk < 72; ++kk) {
            const int tap = kk >> 3;
            const int t3 = tap / 3;
            const int oh = t3 - 1;
            const int ow = (tap - t3 * 3) - 1;
            const int ci0 = (kk & 7) * 16 + lhi * 8;
            const int kb = kk * 2 + lhi;

            bf16x8 bfrag[2];
            #pragma unroll
            for (int t2 = 0; t2 < 2; ++t2) {
                const int co = (wn * 2 + t2) * 32 + lrow;
                bfrag[t2] = __builtin_bit_cast(bf16x8,
                    *(const ushort8_t*)(Bpl + ((size_t)(kb * 128 + co)) * 8));
            }
            bf16x8 afrag[2];
            #pragma unroll
            for (int t = 0; t < 2; ++t) {
                const int m = (wm * 2 + t) * 32 + lrow;
                const int h = (m >> 4) + oh;
                const int w = (m & 15) + ow;
                ushort8_t v = {0, 0, 0, 0, 0, 0, 0, 0};
                if ((unsigned)h < 16u && (unsigned)w < 16u) {
                    const int m2 = h * 16 + w;
                    const int off = (m2 * 256 + ci0 * 2) ^ ((m2 & 15) << 4);
                    v = *(const ushort8_t*)(lds + off);
                }
                afrag[t] = __builtin_bit_cast(bf16x8, v);
            }
            #pragma unroll
            for (int t = 0; t < 2; ++t)
                #pragma unroll
                for (int t2 = 0; t2 < 2; ++t2)
                    acc[t][t2] = __builtin_amdgcn_mfma_f32_32x32x16_bf16(
                        afrag[t], bfrag[t2], acc[t][t2], 0, 0, 0);
        }

        if (layer < 2) {
            // bias+relu+bf16 into registers (static indices only), then in-place LDS rewrite
            unsigned short pk[2][2][16];
            #pragma unroll
            for (int t = 0; t < 2; ++t)
                #pragma unroll
                for (int t2 = 0; t2 < 2; ++t2) {
                    const int co = (wn * 2 + t2) * 32 + lrow;
                    const float bb = bv[co];
                    #pragma unroll
                    for (int r = 0; r < 16; ++r)
                        pk[t][t2][r] = f2bf(fmaxf(acc[t][t2][r] + bb, 0.0f));
                }
            __syncthreads();   // all waves done reading current activation
            #pragma unroll
            for (int t = 0; t < 2; ++t)
                #pragma unroll
                for (int t2 = 0; t2 < 2; ++t2) {
                    const int co = (wn * 2 + t2) * 32 + lrow;
                    #pragma unroll
                    for (int r = 0; r < 16; ++r) {
                        const int m = (wm * 2 + t) * 32 + (r & 3) + 8 * (r >> 2) + 4 * lhi;
                        const int off = (m * 256 + co * 2) ^ ((m & 15) << 4);
                        *(unsigned short*)(lds + off) = pk[t][t2][r];
                    }
                }
            __syncthreads();   // next layer may read
        } else {
            // final layer: pbu in [u][co][m] bf16, packed 4-wide along m
            #pragma unroll
            for (int t2 = 0; t2 < 2; ++t2) {
                const int co = (wn * 2 + t2) * 32 + lrow;
                const float bb = bv[co];
                #pragma unroll
                for (int t = 0; t < 2; ++t) {
                    const int tmb = (wm * 2 + t) * 32;
                    #pragma unroll
                    for (int rq = 0; rq < 4; ++rq) {
                        const int m0 = tmb + 8 * rq + 4 * lhi;
                        ushort4 pkv;
                        pkv.x = f2bf(fmaxf(acc[t][t2][rq * 4 + 0] + bb, 0.0f));
                        pkv.y = f2bf(fmaxf(acc[t][t2][rq * 4 + 1] + bb, 0.0f));
                        pkv.z = f2bf(fmaxf(acc[t][t2][rq * 4 + 2] + bb, 0.0f));
                        pkv.w = f2bf(fmaxf(acc[t][t2][rq * 4 + 3] + bb, 0.0f));
                        *(ushort4*)(pbu_out + (size_t)u * 32768 + co * 256 + m0) = pkv;
                    }
                }
            }
        }
    }
}

// ------------- Kernel B: segment mean (leader) + broadcast + pbu add -------------
__global__ __launch_bounds__(256) void kB(const float* __restrict__ feats,
                                          const unsigned short* __restrict__ pbu,
                                          const int* __restrict__ addr_g,
                                          const int* __restrict__ key_g,
                                          const int* __restrict__ rank_g,
                                          const int* __restrict__ list_g,
                                          const int* __restrict__ segstart_g,
                                          const int* __restrict__ segcnt_g,
                                          float* __restrict__ out) {
    const int i = blockIdx.y;
    if (rank_g[i] != 0) return;          // only segment leaders work
    const int s = key_g[i];
    const int st = segstart_g[s];
    const int n = segcnt_g[s];
    const int e = blockIdx.x * 1024 + threadIdx.x * 4;
    float sx = 0.f, sy = 0.f, sz = 0.f, sw = 0.f;
    for (int t = 0; t < n; ++t) {
        const int j = list_g[st + t];
        const float4 v = *(const float4*)(feats + (size_t)j * 32768 + e);
        sx += v.x; sy += v.y; sz += v.z; sw += v.w;
    }
    const float inv = 1.0f / (float)n;
    sx *= inv; sy *= inv; sz *= inv; sw *= inv;
    for (int t = 0; t < n; ++t) {
        const int j = list_g[st + t];
        const int a = addr_g[j];
        const ushort4 p = *(const ushort4*)(pbu + (size_t)a * 32768 + e);
        float4 o;
        o.x = sx + bf2f(p.x);
        o.y = sy + bf2f(p.y);
        o.z = sz + bf2f(p.z);
        o.w = sw + bf2f(p.w);
        *(float4*)(out + (size_t)j * 32768 + e) = o;
    }
}

extern "C" void kernel_launch(void* const* d_in, const int* in_sizes, int n_in,
                              void* d_out, int out_size, void* d_ws, size_t ws_size,
                              hipStream_t stream) {
    const int* style   = (const int*)d_in[0];
    const int* cids    = (const int*)d_in[1];
    const float* feats = (const float*)d_in[2];
    const float* bias  = (const float*)d_in[3];
    const float* w1    = (const float*)d_in[4];
    const float* b1    = (const float*)d_in[5];
    const float* w2    = (const float*)d_in[6];
    const float* b2    = (const float*)d_in[7];
    const float* w3    = (const float*)d_in[8];
    const float* b3    = (const float*)d_in[9];
    float* out = (float*)d_out;
    char* ws = (char*)d_ws;

    int* addr_g     = (int*)(ws + 0);
    int* key_g      = (int*)(ws + 6144);
    int* rank_g     = (int*)(ws + 12288);
    int* list_g     = (int*)(ws + 18432);
    int* segstart_g = (int*)(ws + 24576);
    int* segcnt_g   = (int*)(ws + 33280);
    unsigned short* Bp  = (unsigned short*)(ws + 65536);     // 3*147456 bf16
    unsigned short* pbu = (unsigned short*)(ws + 1048576);   // 68*32768 bf16 = 4.25MB

    hipLaunchKernelGGL(kA, dim3(1), dim3(256), 0, stream,
                       style, cids, addr_g, key_g, rank_g, list_g, segstart_g, segcnt_g);
    hipLaunchKernelGGL(kW, dim3(1728), dim3(256), 0, stream, w1, w2, w3, Bp);
    hipLaunchKernelGGL(kConvF, dim3(68), dim3(512), 0, stream,
                       bias, Bp, b1, b2, b3, pbu);
    hipLaunchKernelGGL(kB, dim3(32, NITEM), dim3(256), 0, stream,
                       feats, pbu, addr_g, key_g, rank_g, list_g, segstart_g, segcnt_g, out);
}